// Round 14
// baseline (3551.051 us; speedup 1.0000x reference)
//
#include <hip/hip_runtime.h>
#include <stdint.h>

#define BATCH   16
#define NANCH   25200
#define NCLS    80
#define REC     85
#define MAXDET  300
#define TMAX    50
#define NBUCKET 2048
#define FIN     512
#define PREPS   64   // phase-kernel measurement repeats

// output offsets (floats)
#define OFF_PB 0
#define OFF_PS 19200
#define OFF_PL 24000
#define OFF_PK 28800
#define OFF_TB 33600
#define OFF_TS 36800
#define OFF_TL 37600
#define OFF_TV 38400

__device__ __forceinline__ float opaque_f(float x) { asm volatile("" : "+v"(x)); return x; }

// ---- Kernel A: production (R12 verbatim) ----
__global__ __launch_bounds__(256) void kA(const float* __restrict__ logits,
                                          unsigned* __restrict__ confout,
                                          unsigned* __restrict__ labout) {
    const int wid  = (blockIdx.x * 256 + threadIdx.x) >> 6;
    const int lane = threadIdx.x & 63;
    const int t    = lane >> 2;
    const int j    = lane & 3;
    const int a    = wid * 16 + t;
    const float obj = logits[(size_t)a * REC + 4];
    unsigned cf = 0u;
    if (obj > 0.8f) {
        const float* cls = logits + (size_t)a * REC + 5 + j * 20;
        float v[20];
#pragma unroll
        for (int i = 0; i < 5; ++i) {
            float4 q = *(const float4*)(cls + 4 * i);
            v[4*i+0] = q.x; v[4*i+1] = q.y; v[4*i+2] = q.z; v[4*i+3] = q.w;
        }
        float m = v[0];
#pragma unroll
        for (int i = 1; i < 20; ++i) m = fmaxf(m, v[i]);
        m = fmaxf(m, __shfl_xor(m, 1));
        m = fmaxf(m, __shfl_xor(m, 2));
        int lc = 255;
#pragma unroll
        for (int i = 0; i < 20; ++i) lc = min(lc, (v[i] == m) ? (j * 20 + i) : 255);
        lc = min(lc, __shfl_xor(lc, 1));
        lc = min(lc, __shfl_xor(lc, 2));
        const float conf = obj * m;
        cf = (conf > 0.8f) ? __float_as_uint(conf) : 0u;
        if (j == 0) labout[a] = (unsigned)lc;
    }
    if (j == 0) confout[a] = cf;
}

// ---- kP1: init + histogram + threshold -> tbv ----
__global__ __launch_bounds__(1024) void kP1(const unsigned* __restrict__ confbits,
                                            int* __restrict__ tbv) {
    __shared__ unsigned hist[NBUCKET];
    __shared__ int sTb;
    const int b = blockIdx.x;
    const int tid = threadIdx.x;
    const uint4* cb4 = (const uint4*)(confbits + (size_t)b * NANCH);
#pragma unroll 1
    for (int rep = 0; rep < PREPS; ++rep) {
        for (int i = tid; i < NBUCKET; i += 1024) hist[i] = 0u;
        __syncthreads();
#pragma unroll 1
        for (int i = tid; i < NANCH / 4; i += 1024) {
            uint4 u = cb4[i];
            unsigned w0 = u.x, w1 = u.y, w2 = u.z, w3 = u.w;
            if (w0) { unsigned bk = (w0 - 0x3F4CCCCDu) >> 11; if (bk > NBUCKET-1u) bk = NBUCKET-1u; atomicAdd(&hist[bk], 1u); }
            if (w1) { unsigned bk = (w1 - 0x3F4CCCCDu) >> 11; if (bk > NBUCKET-1u) bk = NBUCKET-1u; atomicAdd(&hist[bk], 1u); }
            if (w2) { unsigned bk = (w2 - 0x3F4CCCCDu) >> 11; if (bk > NBUCKET-1u) bk = NBUCKET-1u; atomicAdd(&hist[bk], 1u); }
            if (w3) { unsigned bk = (w3 - 0x3F4CCCCDu) >> 11; if (bk > NBUCKET-1u) bk = NBUCKET-1u; atomicAdd(&hist[bk], 1u); }
        }
        __syncthreads();
        if (tid < 64) {
            const int l = tid;
            unsigned sup = 0u;
            for (int jj = 0; jj < 32; ++jj) sup += hist[l * 32 + jj];
            unsigned ss = sup;
            for (int off = 1; off < 64; off <<= 1) {
                unsigned vv = __shfl_down(ss, off);
                ss += (l + off < 64) ? vv : 0u;
            }
            bool ge = ss >= MAXDET;
            unsigned long long mask = __ballot(ge);
            int sstar = (mask == 0ull) ? 0 : (63 - __clzll(mask));
            unsigned tail = (sstar < 63) ? __shfl(ss, sstar + 1) : 0u;
            unsigned h = (l < 32) ? hist[sstar * 32 + l] : 0u;
            unsigned s2 = h;
            for (int off = 1; off < 32; off <<= 1) {
                unsigned vv = __shfl_down(s2, off);
                s2 += (l + off < 32) ? vv : 0u;
            }
            bool ge2 = (l < 32) && (s2 + tail >= MAXDET);
            unsigned long long m2 = __ballot(ge2);
            int lstar = (m2 == 0ull) ? 0 : (63 - __clzll(m2));
            if (l == 0) sTb = sstar * 32 + lstar;
        }
        __syncthreads();
        if (tid == 0) tbv[b * 16] = sTb;
        __syncthreads();
        asm volatile("" ::: "memory");
    }
}

// ---- kP2: compact -> finv/fcv ----
__global__ __launch_bounds__(1024) void kP2(const unsigned* __restrict__ confbits,
                                            const int* __restrict__ tbv,
                                            unsigned long long* __restrict__ finv,
                                            int* __restrict__ fcv) {
    __shared__ unsigned long long fin[FIN];
    __shared__ int sCnt;
    const int b = blockIdx.x;
    const int tid = threadIdx.x;
    const int lane = tid & 63;
    const uint4* cb4 = (const uint4*)(confbits + (size_t)b * NANCH);
#pragma unroll 1
    for (int rep = 0; rep < PREPS; ++rep) {
        if (tid == 0) sCnt = 0;
        __syncthreads();
        const int tb = tbv[b * 16];
#pragma unroll 1
        for (int i = tid; i < NANCH / 4; i += 1024) {
            uint4 u = cb4[i];
            unsigned wsv[4] = {u.x, u.y, u.z, u.w};
#pragma unroll
            for (int c = 0; c < 4; ++c) {
                unsigned bits = wsv[c];
                unsigned bk = (bits - 0x3F4CCCCDu) >> 11;
                if (bk > NBUCKET - 1u) bk = NBUCKET - 1u;
                bool pass = bits && ((int)bk >= tb);
                unsigned long long mk = __ballot(pass);
                if (mk) {
                    int base = 0;
                    if (lane == 0) base = atomicAdd(&sCnt, __popcll(mk));
                    base = __shfl(base, 0);
                    if (pass) {
                        int p = base + __popcll(mk & ((1ull << lane) - 1ull));
                        if (p < FIN)
                            fin[p] = ((unsigned long long)bits << 32) |
                                     (unsigned)(0xFFFFFFFFu - (unsigned)(i * 4 + c));
                    }
                }
            }
        }
        __syncthreads();
        int fc = (sCnt < FIN) ? sCnt : FIN;
        if (tid < FIN) finv[(size_t)b * FIN + tid] = (tid < fc) ? fin[tid] : 0ull;
        if (tid == 0) fcv[b * 16] = fc;
        __syncthreads();
        asm volatile("" ::: "memory");
    }
}

// ---- kP3: rank-scatter sort -> srtv ----
__global__ __launch_bounds__(1024) void kP3(const unsigned long long* __restrict__ finv,
                                            const int* __restrict__ fcv,
                                            unsigned long long* __restrict__ srtv) {
    __shared__ unsigned long long fin[FIN];
    __shared__ unsigned long long srt[MAXDET];
    const int b = blockIdx.x;
    const int tid = threadIdx.x;
#pragma unroll 1
    for (int rep = 0; rep < PREPS; ++rep) {
        const int fc = fcv[b * 16];
        if (tid < FIN) fin[tid] = finv[(size_t)b * FIN + tid];
        if (tid < MAXDET) srt[tid] = 0ull;
        __syncthreads();
        if (tid < fc) {
            unsigned long long k = fin[tid];
            int r = 0;
            for (int jj = 0; jj < fc; ++jj) r += (fin[jj] > k) ? 1 : 0;
            if (r < MAXDET) srt[r] = k;
        }
        __syncthreads();
        if (tid < MAXDET) srtv[(size_t)b * 320 + tid] = srt[tid];
        __syncthreads();
        asm volatile("" ::: "memory");
    }
}

// ---- kP4: gather -> boxv/areav/scorv/labv ----
__global__ __launch_bounds__(1024) void kP4(const float* __restrict__ logits,
                                            const unsigned* __restrict__ labels,
                                            const unsigned long long* __restrict__ srtv,
                                            float4* __restrict__ boxv,
                                            float* __restrict__ areav,
                                            float* __restrict__ scorv,
                                            unsigned* __restrict__ labv) {
    const int b = blockIdx.x;
    const int tid = threadIdx.x;
#pragma unroll 1
    for (int rep = 0; rep < PREPS; ++rep) {
        if (tid < MAXDET) {
            unsigned long long key = srtv[(size_t)b * 320 + tid];
            float score = __uint_as_float((unsigned)(key >> 32));
            unsigned n = 0xFFFFFFFFu - (unsigned)(key & 0xFFFFFFFFull);
            if (n >= NANCH) n = 0;
            const size_t ga = (size_t)b * NANCH + n;
            float4 bq = *(const float4*)(logits + ga * REC);
            unsigned lab = labels[ga];
            float hw = opaque_f(bq.z * 0.5f);
            float hh = opaque_f(bq.w * 0.5f);
            float x1 = bq.x - hw, y1 = bq.y - hh, x2 = bq.x + hw, y2 = bq.y + hh;
            boxv[(size_t)b * MAXDET + tid] = make_float4(x1, y1, x2, y2);
            areav[(size_t)b * MAXDET + tid] = (x2 - x1) * (y2 - y1);
            scorv[(size_t)b * MAXDET + tid] = score;
            labv[(size_t)b * MAXDET + tid] = lab;
        }
        __syncthreads();
        asm volatile("" ::: "memory");
    }
}

// ---- kP5: suppression-matrix build -> suppv ----
__global__ __launch_bounds__(1024) void kP5(const float4* __restrict__ boxv,
                                            const float* __restrict__ areav,
                                            unsigned* __restrict__ suppv) {
    __shared__ float bx1[MAXDET], by1[MAXDET], bx2[MAXDET], by2[MAXDET];
    __shared__ float sar[MAXDET];
    const int b = blockIdx.x;
    const int tid = threadIdx.x;
    const int lane = tid & 63;
    const int w = tid >> 6;
    unsigned* sg = suppv + (size_t)b * 3008;
#pragma unroll 1
    for (int rep = 0; rep < PREPS; ++rep) {
        if (tid < MAXDET) {
            float4 q = boxv[(size_t)b * MAXDET + tid];
            bx1[tid] = q.x; by1[tid] = q.y; bx2[tid] = q.z; by2[tid] = q.w;
            sar[tid] = areav[(size_t)b * MAXDET + tid];
        }
        __syncthreads();
        for (int i = w; i < MAXDET; i += 16) {
            float p1 = bx1[i], q1 = by1[i], p2 = bx2[i], q2 = by2[i];
            float ai = sar[i];
#pragma unroll
            for (int c = 0; c < 5; ++c) {
                int jj = c * 64 + lane;
                bool pass = false;
                if (jj < MAXDET && jj > i) {
                    float ltx = fmaxf(p1, bx1[jj]);
                    float lty = fmaxf(q1, by1[jj]);
                    float rbx = fminf(p2, bx2[jj]);
                    float rby = fminf(q2, by2[jj]);
                    float wx = fmaxf(rbx - ltx, 0.0f);
                    float wy = fmaxf(rby - lty, 0.0f);
                    float inter = wx * wy;
                    float iou = inter / (ai + sar[jj] - inter + 1e-9f);
                    pass = (iou > 0.4f);
                }
                unsigned long long mk = __ballot(pass);
                if (lane == 0)  sg[i * 10 + 2 * c]     = (unsigned)mk;
                if (lane == 32) sg[i * 10 + 2 * c + 1] = (unsigned)(mk >> 32);
            }
        }
        __syncthreads();
        asm volatile("" ::: "memory");
    }
}

// ---- kP6: greedy scan -> keepv ----
__global__ __launch_bounds__(1024) void kP6(const unsigned* __restrict__ suppv,
                                            unsigned* __restrict__ keepv) {
    __shared__ unsigned supp[MAXDET * 10];
    __shared__ unsigned keepw[10];
    const int b = blockIdx.x;
    const int tid = threadIdx.x;
    const unsigned* sg = suppv + (size_t)b * 3008;
#pragma unroll 1
    for (int rep = 0; rep < PREPS; ++rep) {
        for (int t = tid; t < MAXDET * 10; t += 1024) supp[t] = sg[t];
        __syncthreads();
        if (tid < 64) {
            int q = tid;
            unsigned kw = (q < 10) ? ((q == 9) ? 0xFFFu : 0xFFFFFFFFu) : 0u;
            unsigned nextrow = (q < 10) ? supp[q] : 0u;
            for (int i = 0; i < MAXDET; ++i) {
                unsigned rowq = nextrow;
                if (q < 10 && i + 1 < MAXDET) nextrow = supp[(i + 1) * 10 + q];
                bool mybit = (q == (i >> 5)) && ((kw >> (i & 31)) & 1u);
                if (__ballot(mybit)) kw &= ~rowq;
            }
            if (q < 10) keepw[q] = kw;
        }
        __syncthreads();
        if (tid < 10) keepv[b * 16 + tid] = keepw[tid];
        __syncthreads();
        asm volatile("" ::: "memory");
    }
}

// ---- kFused: production (R12 verbatim) ----
__global__ __launch_bounds__(1024) void kFused(const float* __restrict__ logits,
                                               const unsigned* __restrict__ confbits,
                                               const unsigned* __restrict__ labels,
                                               const float* __restrict__ targets,
                                               const int* __restrict__ tlen,
                                               float* __restrict__ out) {
    __shared__ unsigned hist[NBUCKET];
    __shared__ unsigned long long fin[FIN];
    __shared__ unsigned long long srt[MAXDET];
    __shared__ float bx1[MAXDET], by1[MAXDET], bx2[MAXDET], by2[MAXDET];
    __shared__ float sar[MAXDET];
    __shared__ unsigned supp[MAXDET * 10];
    __shared__ unsigned keepw[10];
    __shared__ int sTb, sCnt;
    const int b = blockIdx.x;
    const int tid = threadIdx.x;
    const int lane = tid & 63;
    const int w = tid >> 6;

    if (tid >= 512 && tid < 512 + TMAX) {
        int t = tid - 512;
        bool is64 = (tlen[1] == 0) && (tlen[3] == 0) && (tlen[5] == 0);
        int len = is64 ? tlen[2 * b] : tlen[b];
        const float* r = targets + ((size_t)b * TMAX + t) * 6;
        float cx = r[0], cy = r[1], wd = r[2], h = r[3], sc = r[4], lb = r[5];
        float hw = opaque_f(wd * 0.5f);
        float hh = opaque_f(h * 0.5f);
        size_t o = (size_t)b * TMAX + t;
        out[OFF_TB + o * 4 + 0] = cx - hw;
        out[OFF_TB + o * 4 + 1] = cy - hh;
        out[OFF_TB + o * 4 + 2] = cx + hw;
        out[OFF_TB + o * 4 + 3] = cy + hh;
        out[OFF_TS + o] = sc;
        out[OFF_TL + o] = (float)(int)lb;
        out[OFF_TV + o] = (t < len) ? 1.0f : 0.0f;
    }

    for (int i = tid; i < NBUCKET; i += 1024) hist[i] = 0u;
    if (tid < MAXDET) srt[tid] = 0ull;
    if (tid == 0) sCnt = 0;
    __syncthreads();

    const unsigned* cb = confbits + (size_t)b * NANCH;
    const uint4* cb4 = (const uint4*)cb;
#pragma unroll 1
    for (int i = tid; i < NANCH / 4; i += 1024) {
        uint4 u = cb4[i];
        unsigned w0 = u.x, w1 = u.y, w2 = u.z, w3 = u.w;
        if (w0) { unsigned bk = (w0 - 0x3F4CCCCDu) >> 11; if (bk > NBUCKET-1u) bk = NBUCKET-1u; atomicAdd(&hist[bk], 1u); }
        if (w1) { unsigned bk = (w1 - 0x3F4CCCCDu) >> 11; if (bk > NBUCKET-1u) bk = NBUCKET-1u; atomicAdd(&hist[bk], 1u); }
        if (w2) { unsigned bk = (w2 - 0x3F4CCCCDu) >> 11; if (bk > NBUCKET-1u) bk = NBUCKET-1u; atomicAdd(&hist[bk], 1u); }
        if (w3) { unsigned bk = (w3 - 0x3F4CCCCDu) >> 11; if (bk > NBUCKET-1u) bk = NBUCKET-1u; atomicAdd(&hist[bk], 1u); }
    }
    __syncthreads();

    if (tid < 64) {
        const int l = tid;
        unsigned sup = 0u;
        for (int j = 0; j < 32; ++j) sup += hist[l * 32 + j];
        unsigned ss = sup;
        for (int off = 1; off < 64; off <<= 1) {
            unsigned v = __shfl_down(ss, off);
            ss += (l + off < 64) ? v : 0u;
        }
        bool ge = ss >= MAXDET;
        unsigned long long mask = __ballot(ge);
        int sstar = (mask == 0ull) ? 0 : (63 - __clzll(mask));
        unsigned tail = (sstar < 63) ? __shfl(ss, sstar + 1) : 0u;
        unsigned h = (l < 32) ? hist[sstar * 32 + l] : 0u;
        unsigned s2 = h;
        for (int off = 1; off < 32; off <<= 1) {
            unsigned v = __shfl_down(s2, off);
            s2 += (l + off < 32) ? v : 0u;
        }
        bool ge2 = (l < 32) && (s2 + tail >= MAXDET);
        unsigned long long m2 = __ballot(ge2);
        int lstar = (m2 == 0ull) ? 0 : (63 - __clzll(m2));
        if (l == 0) sTb = sstar * 32 + lstar;
    }
    __syncthreads();

    const int tb = sTb;
#pragma unroll 1
    for (int i = tid; i < NANCH / 4; i += 1024) {
        uint4 u = cb4[i];
        unsigned wsv[4] = {u.x, u.y, u.z, u.w};
#pragma unroll
        for (int c = 0; c < 4; ++c) {
            unsigned bits = wsv[c];
            unsigned bk = (bits - 0x3F4CCCCDu) >> 11;
            if (bk > NBUCKET - 1u) bk = NBUCKET - 1u;
            bool pass = bits && ((int)bk >= tb);
            unsigned long long mk = __ballot(pass);
            if (mk) {
                int base = 0;
                if (lane == 0) base = atomicAdd(&sCnt, __popcll(mk));
                base = __shfl(base, 0);
                if (pass) {
                    int p = base + __popcll(mk & ((1ull << lane) - 1ull));
                    if (p < FIN)
                        fin[p] = ((unsigned long long)bits << 32) |
                                 (unsigned)(0xFFFFFFFFu - (unsigned)(i * 4 + c));
                }
            }
        }
    }
    __syncthreads();
    const int fc = (sCnt < FIN) ? sCnt : FIN;

    if (tid < fc) {
        unsigned long long k = fin[tid];
        int r = 0;
        for (int j = 0; j < fc; ++j) r += (fin[j] > k) ? 1 : 0;
        if (r < MAXDET) srt[r] = k;
    }
    __syncthreads();

    if (tid < MAXDET) {
        unsigned long long key = srt[tid];
        float score = __uint_as_float((unsigned)(key >> 32));
        unsigned n = 0xFFFFFFFFu - (unsigned)(key & 0xFFFFFFFFull);
        if (n >= NANCH) n = 0;
        const size_t ga = (size_t)b * NANCH + n;
        float4 bq = *(const float4*)(logits + ga * REC);
        unsigned lab = labels[ga];
        float hw = opaque_f(bq.z * 0.5f);
        float hh = opaque_f(bq.w * 0.5f);
        float x1 = bq.x - hw, y1 = bq.y - hh, x2 = bq.x + hw, y2 = bq.y + hh;
        bx1[tid] = x1; by1[tid] = y1; bx2[tid] = x2; by2[tid] = y2;
        sar[tid] = (x2 - x1) * (y2 - y1);
        size_t o = (size_t)(b * MAXDET + tid);
        out[OFF_PB + o * 4 + 0] = x1;
        out[OFF_PB + o * 4 + 1] = y1;
        out[OFF_PB + o * 4 + 2] = x2;
        out[OFF_PB + o * 4 + 3] = y2;
        out[OFF_PS + o] = score;
        out[OFF_PL + o] = (float)lab;
    }
    __syncthreads();

    for (int i = w; i < MAXDET; i += 16) {
        float p1 = bx1[i], q1 = by1[i], p2 = bx2[i], q2 = by2[i];
        float ai = sar[i];
#pragma unroll
        for (int c = 0; c < 5; ++c) {
            int j = c * 64 + lane;
            bool pass = false;
            if (j < MAXDET && j > i) {
                float ltx = fmaxf(p1, bx1[j]);
                float lty = fmaxf(q1, by1[j]);
                float rbx = fminf(p2, bx2[j]);
                float rby = fminf(q2, by2[j]);
                float wx = fmaxf(rbx - ltx, 0.0f);
                float wy = fmaxf(rby - lty, 0.0f);
                float inter = wx * wy;
                float iou = inter / (ai + sar[j] - inter + 1e-9f);
                pass = (iou > 0.4f);
            }
            unsigned long long mk = __ballot(pass);
            if (lane == 0)  supp[i * 10 + 2 * c]     = (unsigned)mk;
            if (lane == 32) supp[i * 10 + 2 * c + 1] = (unsigned)(mk >> 32);
        }
    }
    __syncthreads();

    if (tid < 64) {
        int q = tid;
        unsigned kw = (q < 10) ? ((q == 9) ? 0xFFFu : 0xFFFFFFFFu) : 0u;
        unsigned nextrow = (q < 10) ? supp[q] : 0u;
        for (int i = 0; i < MAXDET; ++i) {
            unsigned rowq = nextrow;
            if (q < 10 && i + 1 < MAXDET) nextrow = supp[(i + 1) * 10 + q];
            bool mybit = (q == (i >> 5)) && ((kw >> (i & 31)) & 1u);
            if (__ballot(mybit)) kw &= ~rowq;
        }
        if (q < 10) keepw[q] = kw;
    }
    __syncthreads();
    if (tid < MAXDET)
        out[OFF_PK + (size_t)b * MAXDET + tid] =
            ((keepw[tid >> 5] >> (tid & 31)) & 1u) ? 1.0f : 0.0f;
}

extern "C" void kernel_launch(void* const* d_in, const int* in_sizes, int n_in,
                              void* d_out, int out_size, void* d_ws, size_t ws_size,
                              hipStream_t stream) {
    const float* logits  = (const float*)d_in[0];
    const float* targets = (const float*)d_in[1];
    const int*   tlen    = (const int*)d_in[2];
    float* out = (float*)d_out;
    char* ws = (char*)d_ws;
    unsigned* confbits = (unsigned*)ws;                                 // 403200 u32
    unsigned* labels   = (unsigned*)(ws + 1612800);                     // 403200 u32
    char* S = ws + 3225600;
    int* tbv                  = (int*)(S);                              // 16x16 int
    int* fcv                  = (int*)(S + 1024);
    unsigned long long* finv  = (unsigned long long*)(S + 2048);        // 16x512 u64
    unsigned long long* srtv  = (unsigned long long*)(S + 67584);       // 16x320 u64
    float4* boxv              = (float4*)(S + 108544);                  // 16x300 f4
    float* areav              = (float*)(S + 185344);                   // 16x300 f32
    float* scorv              = (float*)(S + 204544);
    unsigned* labv            = (unsigned*)(S + 223744);
    unsigned* suppv           = (unsigned*)(S + 242944);                // 16x3008 u32
    unsigned* keepv           = (unsigned*)(S + 435456);                // 16x16 u32

    hipLaunchKernelGGL(kA, dim3(6300), dim3(256), 0, stream, logits, confbits, labels);
    hipLaunchKernelGGL(kP1, dim3(BATCH), dim3(1024), 0, stream, confbits, tbv);
    hipLaunchKernelGGL(kP2, dim3(BATCH), dim3(1024), 0, stream, confbits, tbv, finv, fcv);
    hipLaunchKernelGGL(kP3, dim3(BATCH), dim3(1024), 0, stream, finv, fcv, srtv);
    hipLaunchKernelGGL(kP4, dim3(BATCH), dim3(1024), 0, stream,
                       logits, labels, srtv, boxv, areav, scorv, labv);
    hipLaunchKernelGGL(kP5, dim3(BATCH), dim3(1024), 0, stream, boxv, areav, suppv);
    hipLaunchKernelGGL(kP6, dim3(BATCH), dim3(1024), 0, stream, suppv, keepv);
    hipLaunchKernelGGL(kFused, dim3(BATCH), dim3(1024), 0, stream,
                       logits, confbits, labels, targets, tlen, out);
}

// Round 15
// 72.232 us; speedup vs baseline: 49.1619x; 49.1619x over previous
//
#include <hip/hip_runtime.h>
#include <stdint.h>

#define BATCH   16
#define NANCH   25200
#define NCLS    80
#define REC     85
#define MAXDET  300
#define TMAX    50
#define NBUCKET 2048
#define FIN     512
#define SUPW    3008   // padded words per batch for supp matrix (300*10 used)

// output offsets (floats)
#define OFF_PB 0
#define OFF_PS 19200
#define OFF_PL 24000
#define OFF_PK 28800
#define OFF_TB 33600
#define OFF_TS 36800
#define OFF_TL 37600
#define OFF_TV 38400

__device__ __forceinline__ float opaque_f(float x) { asm volatile("" : "+v"(x)); return x; }

// ---- Kernel A: score+label, obj-gated (conf>0.8 requires obj>0.8) ----
__global__ __launch_bounds__(256) void kA(const float* __restrict__ logits,
                                          unsigned* __restrict__ confout,
                                          unsigned* __restrict__ labout) {
    const int wid  = (blockIdx.x * 256 + threadIdx.x) >> 6;
    const int lane = threadIdx.x & 63;
    const int t    = lane >> 2;
    const int j    = lane & 3;
    const int a    = wid * 16 + t;
    const float obj = logits[(size_t)a * REC + 4];
    unsigned cf = 0u;
    if (obj > 0.8f) {
        const float* cls = logits + (size_t)a * REC + 5 + j * 20;
        float v[20];
#pragma unroll
        for (int i = 0; i < 5; ++i) {
            float4 q = *(const float4*)(cls + 4 * i);
            v[4*i+0] = q.x; v[4*i+1] = q.y; v[4*i+2] = q.z; v[4*i+3] = q.w;
        }
        float m = v[0];
#pragma unroll
        for (int i = 1; i < 20; ++i) m = fmaxf(m, v[i]);
        m = fmaxf(m, __shfl_xor(m, 1));
        m = fmaxf(m, __shfl_xor(m, 2));
        int lc = 255;
#pragma unroll
        for (int i = 0; i < 20; ++i) lc = min(lc, (v[i] == m) ? (j * 20 + i) : 255);
        lc = min(lc, __shfl_xor(lc, 1));
        lc = min(lc, __shfl_xor(lc, 2));
        const float conf = obj * m;                           // exact: single multiply
        cf = (conf > 0.8f) ? __float_as_uint(conf) : 0u;
        if (j == 0) labout[a] = (unsigned)lc;
    }
    if (j == 0) confout[a] = cf;
}

// ---- kSel: select top-300 + sort + gather + pred outputs + targets ----
__global__ __launch_bounds__(1024) void kSel(const float* __restrict__ logits,
                                             const unsigned* __restrict__ confbits,
                                             const unsigned* __restrict__ labels,
                                             const float* __restrict__ targets,
                                             const int* __restrict__ tlen,
                                             float* __restrict__ out) {
    __shared__ unsigned hist[NBUCKET];
    __shared__ unsigned long long fin[FIN];
    __shared__ unsigned long long srt[MAXDET];
    __shared__ int sTb, sCnt;
    const int b = blockIdx.x;
    const int tid = threadIdx.x;
    const int lane = tid & 63;

    // ---- targets, folded into spare threads ----
    if (tid >= 512 && tid < 512 + TMAX) {
        int t = tid - 512;
        bool is64 = (tlen[1] == 0) && (tlen[3] == 0) && (tlen[5] == 0);
        int len = is64 ? tlen[2 * b] : tlen[b];
        const float* r = targets + ((size_t)b * TMAX + t) * 6;
        float cx = r[0], cy = r[1], w = r[2], h = r[3], sc = r[4], lb = r[5];
        float hw = opaque_f(w * 0.5f);
        float hh = opaque_f(h * 0.5f);
        size_t o = (size_t)b * TMAX + t;
        out[OFF_TB + o * 4 + 0] = cx - hw;
        out[OFF_TB + o * 4 + 1] = cy - hh;
        out[OFF_TB + o * 4 + 2] = cx + hw;
        out[OFF_TB + o * 4 + 3] = cy + hh;
        out[OFF_TS + o] = sc;
        out[OFF_TL + o] = (float)(int)lb;
        out[OFF_TV + o] = (t < len) ? 1.0f : 0.0f;
    }

    // ---- init ----
    for (int i = tid; i < NBUCKET; i += 1024) hist[i] = 0u;
    if (tid < MAXDET) srt[tid] = 0ull;
    if (tid == 0) sCnt = 0;
    __syncthreads();

    // ---- histogram (loads pipeline: no unroll clamp) ----
    const unsigned* cb = confbits + (size_t)b * NANCH;
    const uint4* cb4 = (const uint4*)cb;
    for (int i = tid; i < NANCH / 4; i += 1024) {
        uint4 u = cb4[i];
        unsigned w0 = u.x, w1 = u.y, w2 = u.z, w3 = u.w;
        if (w0) { unsigned bk = (w0 - 0x3F4CCCCDu) >> 11; if (bk > NBUCKET-1u) bk = NBUCKET-1u; atomicAdd(&hist[bk], 1u); }
        if (w1) { unsigned bk = (w1 - 0x3F4CCCCDu) >> 11; if (bk > NBUCKET-1u) bk = NBUCKET-1u; atomicAdd(&hist[bk], 1u); }
        if (w2) { unsigned bk = (w2 - 0x3F4CCCCDu) >> 11; if (bk > NBUCKET-1u) bk = NBUCKET-1u; atomicAdd(&hist[bk], 1u); }
        if (w3) { unsigned bk = (w3 - 0x3F4CCCCDu) >> 11; if (bk > NBUCKET-1u) bk = NBUCKET-1u; atomicAdd(&hist[bk], 1u); }
    }
    __syncthreads();

    // ---- threshold bucket tb, wave 0 ----
    if (tid < 64) {
        const int l = tid;
        unsigned sup = 0u;
        for (int j = 0; j < 32; ++j) sup += hist[l * 32 + j];
        unsigned ss = sup;
        for (int off = 1; off < 64; off <<= 1) {
            unsigned v = __shfl_down(ss, off);
            ss += (l + off < 64) ? v : 0u;
        }
        bool ge = ss >= MAXDET;
        unsigned long long mask = __ballot(ge);
        int sstar = (mask == 0ull) ? 0 : (63 - __clzll(mask));
        unsigned tail = (sstar < 63) ? __shfl(ss, sstar + 1) : 0u;
        unsigned h = (l < 32) ? hist[sstar * 32 + l] : 0u;
        unsigned s2 = h;
        for (int off = 1; off < 32; off <<= 1) {
            unsigned v = __shfl_down(s2, off);
            s2 += (l + off < 32) ? v : 0u;
        }
        bool ge2 = (l < 32) && (s2 + tail >= MAXDET);
        unsigned long long m2 = __ballot(ge2);
        int lstar = (m2 == 0ull) ? 0 : (63 - __clzll(m2));
        if (l == 0) sTb = sstar * 32 + lstar;
    }
    __syncthreads();

    // ---- compact >= threshold; wave-aggregated atomics (pipelined loads) ----
    const int tb = sTb;
    for (int i = tid; i < NANCH / 4; i += 1024) {
        uint4 u = cb4[i];
        unsigned wsv[4] = {u.x, u.y, u.z, u.w};
#pragma unroll
        for (int c = 0; c < 4; ++c) {
            unsigned bits = wsv[c];
            unsigned bk = (bits - 0x3F4CCCCDu) >> 11;
            if (bk > NBUCKET - 1u) bk = NBUCKET - 1u;
            bool pass = bits && ((int)bk >= tb);
            unsigned long long mk = __ballot(pass);
            if (mk) {
                int base = 0;
                if (lane == 0) base = atomicAdd(&sCnt, __popcll(mk));
                base = __shfl(base, 0);
                if (pass) {
                    int p = base + __popcll(mk & ((1ull << lane) - 1ull));
                    if (p < FIN)
                        fin[p] = ((unsigned long long)bits << 32) |
                                 (unsigned)(0xFFFFFFFFu - (unsigned)(i * 4 + c));
                }
            }
        }
    }
    __syncthreads();
    const int fc = (sCnt < FIN) ? sCnt : FIN;

    // ---- rank-scatter sort ----
    if (tid < fc) {
        unsigned long long k = fin[tid];
        int r = 0;
        for (int j = 0; j < fc; ++j) r += (fin[j] > k) ? 1 : 0;
        if (r < MAXDET) srt[r] = k;
    }
    __syncthreads();

    // ---- gather top-300: box float4 + precomputed label ----
    if (tid < MAXDET) {
        unsigned long long key = srt[tid];
        float score = __uint_as_float((unsigned)(key >> 32));
        unsigned n = 0xFFFFFFFFu - (unsigned)(key & 0xFFFFFFFFull);
        if (n >= NANCH) n = 0;
        const size_t ga = (size_t)b * NANCH + n;
        float4 bq = *(const float4*)(logits + ga * REC);
        unsigned lab = labels[ga];
        float hw = opaque_f(bq.z * 0.5f);  // block FMA contraction: match XLA rounding
        float hh = opaque_f(bq.w * 0.5f);
        float x1 = bq.x - hw, y1 = bq.y - hh, x2 = bq.x + hw, y2 = bq.y + hh;
        size_t o = (size_t)(b * MAXDET + tid);
        out[OFF_PB + o * 4 + 0] = x1;
        out[OFF_PB + o * 4 + 1] = y1;
        out[OFF_PB + o * 4 + 2] = x2;
        out[OFF_PB + o * 4 + 3] = y2;
        out[OFF_PS + o] = score;
        out[OFF_PL + o] = (float)lab;
    }
}

// ---- kSup: suppression bitmatrix, 8 row-strip blocks per batch (8 CUs) ----
__global__ __launch_bounds__(256) void kSup(const float* __restrict__ out,
                                            unsigned* __restrict__ suppg) {
    __shared__ float4 sb[MAXDET];
    __shared__ float sar[MAXDET];
    const int b = blockIdx.x >> 3;
    const int s = blockIdx.x & 7;
    const int tid = threadIdx.x;
    const int lane = tid & 63;
    const int w = tid >> 6;                       // wave 0..3
    const float4* boxes = (const float4*)(out + OFF_PB) + (size_t)b * MAXDET;
    for (int t = tid; t < MAXDET; t += 256) {
        float4 q = boxes[t];
        sb[t] = q;
        sar[t] = (q.z - q.x) * (q.w - q.y);       // same floats as reference area
    }
    __syncthreads();
    const int i0 = s * 38;
    const int i1 = min(i0 + 38, MAXDET);
    unsigned* sg = suppg + (size_t)b * SUPW;
    for (int i = i0 + w; i < i1; i += 4) {
        float4 bi = sb[i];                         // wave-uniform broadcast
        float ai = sar[i];
#pragma unroll
        for (int c = 0; c < 5; ++c) {
            int j = c * 64 + lane;
            bool pass = false;
            if (j < MAXDET && j > i) {
                float4 bj = sb[j];
                float aj = sar[j];
                float ltx = fmaxf(bi.x, bj.x);
                float lty = fmaxf(bi.y, bj.y);
                float rbx = fminf(bi.z, bj.z);
                float rby = fminf(bi.w, bj.w);
                float wx = fmaxf(rbx - ltx, 0.0f);
                float wy = fmaxf(rby - lty, 0.0f);
                float inter = wx * wy;
                float iou = inter / (ai + aj - inter + 1e-9f);  // left-to-right
                pass = (iou > 0.4f);
            }
            unsigned long long mk = __ballot(pass);
            if (lane == 0)  sg[i * 10 + 2 * c]     = (unsigned)mk;
            if (lane == 32) sg[i * 10 + 2 * c + 1] = (unsigned)(mk >> 32);
        }
    }
}

// ---- kScan: greedy NMS scan over the global bitmatrix ----
__global__ __launch_bounds__(512) void kScan(const unsigned* __restrict__ suppg,
                                             float* __restrict__ out) {
    __shared__ unsigned supp[MAXDET * 10];
    __shared__ unsigned keepw[10];
    const int b = blockIdx.x;
    const int tid = threadIdx.x;
    const unsigned* sg = suppg + (size_t)b * SUPW;
    for (int t = tid; t < MAXDET * 10; t += 512) supp[t] = sg[t];
    __syncthreads();
    if (tid < 64) {
        int q = tid;
        unsigned kw = (q < 10) ? ((q == 9) ? 0xFFFu : 0xFFFFFFFFu) : 0u;
        unsigned nextrow = (q < 10) ? supp[q] : 0u;
        for (int i = 0; i < MAXDET; ++i) {
            unsigned rowq = nextrow;
            if (q < 10 && i + 1 < MAXDET) nextrow = supp[(i + 1) * 10 + q];
            bool mybit = (q == (i >> 5)) && ((kw >> (i & 31)) & 1u);
            if (__ballot(mybit)) kw &= ~rowq;      // rows only contain j>i bits
        }
        if (q < 10) keepw[q] = kw;
    }
    __syncthreads();
    if (tid < MAXDET)
        out[OFF_PK + (size_t)b * MAXDET + tid] =
            ((keepw[tid >> 5] >> (tid & 31)) & 1u) ? 1.0f : 0.0f;
}

extern "C" void kernel_launch(void* const* d_in, const int* in_sizes, int n_in,
                              void* d_out, int out_size, void* d_ws, size_t ws_size,
                              hipStream_t stream) {
    const float* logits  = (const float*)d_in[0];
    const float* targets = (const float*)d_in[1];
    const int*   tlen    = (const int*)d_in[2];
    float* out = (float*)d_out;
    char* ws = (char*)d_ws;
    unsigned* confbits = (unsigned*)ws;                                 // 403200 u32
    unsigned* labels   = (unsigned*)(ws + (size_t)BATCH * NANCH * 4);   // 403200 u32
    unsigned* suppg    = (unsigned*)(ws + (size_t)BATCH * NANCH * 8);   // 16*3008 u32

    hipLaunchKernelGGL(kA, dim3(6300), dim3(256), 0, stream, logits, confbits, labels);
    hipLaunchKernelGGL(kSel, dim3(BATCH), dim3(1024), 0, stream,
                       logits, confbits, labels, targets, tlen, out);
    hipLaunchKernelGGL(kSup, dim3(BATCH * 8), dim3(256), 0, stream, out, suppg);
    hipLaunchKernelGGL(kScan, dim3(BATCH), dim3(512), 0, stream, suppg, out);
}